// Round 10
// baseline (488.134 us; speedup 1.0000x reference)
//
#include <hip/hip_runtime.h>
#include <hip/hip_bf16.h>
#include <math.h>

#define NN    32768      // nodes
#define FIN   128        // input features
#define DD    512        // hidden dim
#define NDOCS 256        // documents
#define NE    262144     // edges
#define NPD   128        // nodes per doc
#define ECAP  32         // fixed CSR capacity per node (P(deg>32) ~ 1e-12)

typedef __attribute__((ext_vector_type(8))) short s16x8;
typedef __attribute__((ext_vector_type(4))) float f32x4;

__device__ __forceinline__ unsigned short f2bf(float f) {
    union { float f; unsigned int u; } v; v.f = f;
    unsigned int r = (v.u + 0x7FFFu + ((v.u >> 16) & 1u)) >> 16;
    return (unsigned short)r;
}
__device__ __forceinline__ float bf2f(unsigned short h) {
    union { unsigned int u; float f; } v; v.u = ((unsigned int)h) << 16;
    return v.f;
}

__device__ __forceinline__ void gl2lds16(const void* g, void* l) {
    __builtin_amdgcn_global_load_lds(
        (const __attribute__((address_space(1))) int*)g,
        (__attribute__((address_space(3))) int*)l, 16, 0, 0);
}

// ---------------------------------------------------------------------------
// graph structure build (fixed-stride CSR: no prefix scan)
// ---------------------------------------------------------------------------
__global__ __launch_bounds__(256) void zero2(int* __restrict__ cnt, int* __restrict__ cursor) {
    int i = blockIdx.x * 256 + threadIdx.x;
    if (i < NN) { cnt[i] = 0; cursor[i] = 0; }
}

__global__ __launch_bounds__(256) void count_deg(const int* __restrict__ dst, int* __restrict__ cnt) {
    int e = blockIdx.x * 256 + threadIdx.x;
    if (e < NE) atomicAdd(&cnt[dst[e]], 1);
}

__global__ __launch_bounds__(256) void dis_k(const int* __restrict__ cnt, float* __restrict__ dis) {
    int i = blockIdx.x * 256 + threadIdx.x;
    if (i < NN) dis[i] = rsqrtf((float)(cnt[i] + 1));
}

__global__ __launch_bounds__(256) void fill_csr(const int* __restrict__ src, const int* __restrict__ dst,
                                                const float* __restrict__ dis,
                                                int* __restrict__ cursor, int* __restrict__ csr_src,
                                                float* __restrict__ csr_norm) {
    int e = blockIdx.x * 256 + threadIdx.x;
    if (e < NE) {
        int d = dst[e];
        int s = src[e];
        int pos = atomicAdd(&cursor[d], 1);
        if (pos < ECAP) {
            csr_src[d * ECAP + pos]  = s;
            csr_norm[d * ECAP + pos] = dis[s] * dis[d];
        }
    }
}

__global__ __launch_bounds__(128) void doc_attn(const float* __restrict__ attn, float* __restrict__ dm) {
    int d = blockIdx.x;
    int t = threadIdx.x;
    float v = attn[d * NPD + t];
    #pragma unroll
    for (int off = 32; off >= 1; off >>= 1) v += __shfl_down(v, off);
    __shared__ float sm[2];
    if ((t & 63) == 0) sm[t >> 6] = v;
    __syncthreads();
    if (t == 0) dm[d] = (sm[0] + sm[1]) * (1.0f / (float)NPD);
}

// ---------------------------------------------------------------------------
// fused dtype prep: x->bf16 and all weight transposes in ONE launch.
// ---------------------------------------------------------------------------
__global__ __launch_bounds__(256) void prep_cvt(const float* __restrict__ x,  unsigned short* __restrict__ xb,
                                                const float* __restrict__ Wi, unsigned short* __restrict__ Wti,
                                                const float* __restrict__ Wh, unsigned short* __restrict__ Wth,
                                                const float* __restrict__ Wo, unsigned short* __restrict__ Wto,
                                                const float* __restrict__ W1, unsigned short* __restrict__ Wt1,
                                                const float* __restrict__ W2, unsigned short* __restrict__ W2t) {
    int idx = blockIdx.x * 256 + threadIdx.x;
    if (idx < 1048576) {                       // cvt_x (float4 units)
        float4 v = ((const float4*)x)[idx];
        ushort4 o;
        o.x = f2bf(v.x); o.y = f2bf(v.y); o.z = f2bf(v.z); o.w = f2bf(v.w);
        ((ushort4*)xb)[idx] = o;
        return;
    }
    idx -= 1048576;
    if (idx < 65536)  { int k = idx >> 9, n = idx & 511; Wti[(size_t)n * FIN + k] = f2bf(Wi[idx]); return; }
    idx -= 65536;
    if (idx < 262144) { int k = idx >> 9, n = idx & 511; Wth[(size_t)n * DD + k] = f2bf(Wh[idx]); return; }
    idx -= 262144;
    if (idx < 262144) { int k = idx >> 9, n = idx & 511; Wto[(size_t)n * DD + k] = f2bf(Wo[idx]); return; }
    idx -= 262144;
    if (idx < 262144) { int k = idx >> 9, n = idx & 511; Wt1[(size_t)n * DD + k] = f2bf(W1[idx]); return; }
    idx -= 262144;
    if (idx < 16384)  { int k = idx >> 5, n = idx & 31;  W2t[(size_t)n * DD + k] = f2bf(W2[idx]); return; }
}

// ---------------------------------------------------------------------------
// MFMA bf16 GEMM: C[MxN] = A[MxK] @ Bt[NxK]^T (optional fused bias+tanh)
// 128x64 tile, 48 KB LDS (3 blocks/CU), T2 XOR swizzle, XCD-chunked block
// swizzle, T4 counted vmcnt(6). Best-known config (r8, 468.9 us total).
// UNCHANGED this round — the agg split below surfaces this kernel's
// counters in the top-5 for the first direct diagnosis.
// ---------------------------------------------------------------------------
template<bool FUSE>
__global__ __launch_bounds__(256) void mfma_gemm(const unsigned short* __restrict__ A,
                                                 const unsigned short* __restrict__ Bt,
                                                 const float* __restrict__ bias,
                                                 unsigned short* __restrict__ C,
                                                 int M, int N, int K) {
    __shared__ __align__(16) unsigned short As[2][128 * 64];   // 32 KB
    __shared__ __align__(16) unsigned short Bs[2][64 * 64];    // 16 KB
    int tid  = threadIdx.x;
    int lane = tid & 63;
    int wave = tid >> 6;

    // XCD-chunked bijective block swizzle (nwg % 8 == 0).
    int nwg  = gridDim.x;
    int bid  = blockIdx.x;
    int bsw  = (bid & 7) * (nwg >> 3) + (bid >> 3);
    int ntiles_n = N >> 6;
    int m0 = (bsw / ntiles_n) * 128;
    int n0 = (bsw % ntiles_n) * 64;

    int wm = wave * 32;            // wave's 32 m-rows; all 64 n-cols

    f32x4 zero = {0.f, 0.f, 0.f, 0.f};
    f32x4 acc[2][4];
    #pragma unroll
    for (int mi = 0; mi < 2; ++mi)
        #pragma unroll
        for (int ni = 0; ni < 4; ++ni) acc[mi][ni] = zero;

    int srow = tid >> 3;                               // 0..31
    // pre-swizzled global source column: slot ^ (row&7), 16B slots
    int scol = (((tid & 7) ^ ((tid >> 3) & 7)) * 8);
    const unsigned short* abase = A  + (size_t)(m0 + srow) * K + scol;
    const unsigned short* bbase = Bt + (size_t)(n0 + srow) * K + scol;

    // prologue: stage tile 0 into buffer 0 (6 vmem ops/wave)
    #pragma unroll
    for (int i = 0; i < 4; ++i)
        gl2lds16(abase + (size_t)i * 32 * K, &As[0][(size_t)(wave * 64 + i * 256) * 8]);
    gl2lds16(bbase,                  &Bs[0][(size_t)(wave * 64) * 8]);
    gl2lds16(bbase + (size_t)32 * K, &Bs[0][(size_t)(wave * 64 + 256) * 8]);

    int nk = K >> 6;
    for (int t = 0; t < nk; ++t) {
        int cur = t & 1;
        if (t + 1 < nk) {                      // stage next tile: 6 vmem ops
            int nxt = cur ^ 1;
            int k0n = (t + 1) << 6;
            #pragma unroll
            for (int i = 0; i < 4; ++i)
                gl2lds16(abase + (size_t)i * 32 * K + k0n, &As[nxt][(size_t)(wave * 64 + i * 256) * 8]);
            gl2lds16(bbase + k0n,                  &Bs[nxt][(size_t)(wave * 64) * 8]);
            gl2lds16(bbase + (size_t)32 * K + k0n, &Bs[nxt][(size_t)(wave * 64 + 256) * 8]);
            asm volatile("s_waitcnt vmcnt(6)" ::: "memory");   // prev tile staged
        } else {
            asm volatile("s_waitcnt vmcnt(0)" ::: "memory");   // last tile staged
        }
        __builtin_amdgcn_s_barrier();          // B1: buf[cur] visible to all

        s16x8 af[2][2], bfr[4][2];
        #pragma unroll
        for (int ks = 0; ks < 2; ++ks) {
            int soff = (((ks * 4 + (lane >> 4)) ^ (lane & 7)) << 3);   // row&7 == lane&7
            int ar = wm + (lane & 15);
            int br = lane & 15;
            #pragma unroll
            for (int mi = 0; mi < 2; ++mi)
                af[mi][ks] = *(const s16x8*)(&As[cur][0] + (size_t)(ar + mi * 16) * 64 + soff);
            #pragma unroll
            for (int ni = 0; ni < 4; ++ni)
                bfr[ni][ks] = *(const s16x8*)(&Bs[cur][0] + (size_t)(br + ni * 16) * 64 + soff);
        }
        asm volatile("s_waitcnt lgkmcnt(0)" ::: "memory");     // reads retired
        if (t + 1 < nk) __builtin_amdgcn_s_barrier();          // B2: safe to overwrite

        #pragma unroll
        for (int ks = 0; ks < 2; ++ks)
            #pragma unroll
            for (int mi = 0; mi < 2; ++mi)
                #pragma unroll
                for (int ni = 0; ni < 4; ++ni)
                    acc[mi][ni] = __builtin_amdgcn_mfma_f32_16x16x32_bf16(af[mi][ks], bfr[ni][ks], acc[mi][ni], 0, 0, 0);
    }

    int col = lane & 15;
    int rb  = (lane >> 4) * 4;
    #pragma unroll
    for (int ni = 0; ni < 4; ++ni) {
        int n = n0 + ni * 16 + col;
        float bv = 0.f;
        if (FUSE) bv = bias[n];
        #pragma unroll
        for (int mi = 0; mi < 2; ++mi) {
            size_t base = (size_t)(m0 + wm + mi * 16 + rb) * N + n;
            #pragma unroll
            for (int r = 0; r < 4; ++r) {
                float v = acc[mi][ni][r];
                if (FUSE) v = tanhf(v + bv);
                C[base + (size_t)r * N] = f2bf(v);
            }
        }
    }
}

// ---------------------------------------------------------------------------
// 512-wide aggregation (bf16 in/out), one wave per node, fixed-stride CSR.
// SPLIT into two half-dispatches (nbase = 0, NN/2) so each half runs ~31 us
// and the mfma_gemm dispatches surface in the rocprof top-5 (diagnostic).
// Traffic and access pattern identical to the single-dispatch version.
// ---------------------------------------------------------------------------
__global__ __launch_bounds__(256) void agg_bf(const unsigned short* __restrict__ hw,
                                              const float* __restrict__ dis,
                                              const int* __restrict__ cnt,
                                              const int* __restrict__ csr_src,
                                              const float* __restrict__ csr_norm,
                                              const float* __restrict__ bias,
                                              unsigned short* __restrict__ out,
                                              int nbase) {
    int n = nbase + blockIdx.x * 4 + (threadIdx.x >> 6);
    int lane = threadIdx.x & 63;
    int cb = lane * 8;
    int deg = cnt[n];
    int dcap = deg > ECAP ? ECAP : deg;

    int   sidx  = 0;
    float snorm = 0.f;
    if (lane < dcap) {
        sidx  = csr_src[n * ECAP + lane];
        snorm = csr_norm[n * ECAP + lane];
    }

    float dn = dis[n];
    float sw = dn * dn;
    float acc[8];
    s16x8 v = *(const s16x8*)(hw + (size_t)n * DD + cb);
    #pragma unroll
    for (int j = 0; j < 8; ++j) acc[j] = bf2f((unsigned short)v[j]) * sw;

    for (int j0 = 0; j0 < dcap; j0 += 4) {
        int   s0 = __shfl(sidx, j0);
        int   s1 = __shfl(sidx, j0 + 1);
        int   s2 = __shfl(sidx, j0 + 2);
        int   s3 = __shfl(sidx, j0 + 3);
        float w0 = __shfl(snorm, j0);
        float w1 = __shfl(snorm, j0 + 1);
        float w2 = __shfl(snorm, j0 + 2);
        float w3 = __shfl(snorm, j0 + 3);
        s16x8 u0 = *(const s16x8*)(hw + (size_t)s0 * DD + cb);
        s16x8 u1 = *(const s16x8*)(hw + (size_t)s1 * DD + cb);
        s16x8 u2 = *(const s16x8*)(hw + (size_t)s2 * DD + cb);
        s16x8 u3 = *(const s16x8*)(hw + (size_t)s3 * DD + cb);
        #pragma unroll
        for (int j = 0; j < 8; ++j) {
            acc[j] += w0 * bf2f((unsigned short)u0[j]);
            acc[j] += w1 * bf2f((unsigned short)u1[j]);
            acc[j] += w2 * bf2f((unsigned short)u2[j]);
            acc[j] += w3 * bf2f((unsigned short)u3[j]);
        }
    }

    s16x8 o;
    #pragma unroll
    for (int j = 0; j < 8; ++j)
        o[j] = (short)f2bf(tanhf(acc[j] + bias[cb + j]));
    *(s16x8*)(out + (size_t)n * DD + cb) = o;
}

// ---------------------------------------------------------------------------
// layer-1 pre-aggregation on 128-wide x (bf16 in/out, fp32 accum)
// ---------------------------------------------------------------------------
__global__ __launch_bounds__(256) void agg_x(const unsigned short* __restrict__ xb,
                                             const float* __restrict__ dis,
                                             const int* __restrict__ cnt,
                                             const int* __restrict__ csr_src,
                                             const float* __restrict__ csr_norm,
                                             unsigned short* __restrict__ xagg) {
    int n = blockIdx.x * 4 + (threadIdx.x >> 6);
    int lane = threadIdx.x & 63;
    int cb = lane * 2;
    int deg = cnt[n];
    int dcap = deg > ECAP ? ECAP : deg;

    int   sidx  = 0;
    float snorm = 0.f;
    if (lane < dcap) {
        sidx  = csr_src[n * ECAP + lane];
        snorm = csr_norm[n * ECAP + lane];
    }

    float dn = dis[n];
    float sw = dn * dn;
    unsigned int v = *(const unsigned int*)(xb + (size_t)n * FIN + cb);
    float a0 = bf2f((unsigned short)(v & 0xffffu)) * sw;
    float a1 = bf2f((unsigned short)(v >> 16)) * sw;

    for (int j0 = 0; j0 < dcap; j0 += 8) {
        int   s[8];
        float w[8];
        #pragma unroll
        for (int t = 0; t < 8; ++t) {
            s[t] = __shfl(sidx, j0 + t);
            w[t] = __shfl(snorm, j0 + t);
        }
        unsigned int u[8];
        #pragma unroll
        for (int t = 0; t < 8; ++t)
            u[t] = *(const unsigned int*)(xb + (size_t)s[t] * FIN + cb);
        #pragma unroll
        for (int t = 0; t < 8; ++t) {
            a0 += w[t] * bf2f((unsigned short)(u[t] & 0xffffu));
            a1 += w[t] * bf2f((unsigned short)(u[t] >> 16));
        }
    }
    unsigned int o = (unsigned int)f2bf(a0) | ((unsigned int)f2bf(a1) << 16);
    *(unsigned int*)(xagg + (size_t)n * FIN + cb) = o;
}

// ---------------------------------------------------------------------------
// fused fc2+fc3+pool: one block per doc (128 nodes), MFMA 128x32, K=512
// ---------------------------------------------------------------------------
__global__ __launch_bounds__(256) void fc23_pool(const unsigned short* __restrict__ H,
                                                 const unsigned short* __restrict__ W2t,
                                                 const float* __restrict__ b2,
                                                 const float* __restrict__ W3,
                                                 const float* __restrict__ b3,
                                                 float* __restrict__ util) {
    __shared__ __align__(16) unsigned short As[128 * 64];
    __shared__ __align__(16) unsigned short Bs[32 * 64];
    __shared__ float red[4];
    int d = blockIdx.x;
    int tid = threadIdx.x;
    int lane = tid & 63;
    int wave = tid >> 6;
    const unsigned short* A = H + (size_t)d * NPD * DD;

    f32x4 zero = {0.f, 0.f, 0.f, 0.f};
    f32x4 acc[2][2];
    #pragma unroll
    for (int mi = 0; mi < 2; ++mi)
        #pragma unroll
        for (int ni = 0; ni < 2; ++ni) acc[mi][ni] = zero;

    int srow = tid >> 3;
    int scol = (((tid & 7) ^ ((tid >> 3) & 7)) * 8);
    for (int k0 = 0; k0 < DD; k0 += 64) {
        __syncthreads();
        #pragma unroll
        for (int i = 0; i < 4; ++i)
            gl2lds16(A + (size_t)(srow + i * 32) * DD + k0 + scol,
                     As + (size_t)(wave * 64 + i * 256) * 8);
        gl2lds16(W2t + (size_t)srow * DD + k0 + scol, Bs + (size_t)(wave * 64) * 8);
        __syncthreads();
        #pragma unroll
        for (int ks = 0; ks < 2; ++ks) {
            int slotbase = ks * 4 + (lane >> 4);
            int soff = ((slotbase ^ (lane & 7)) << 3);
            s16x8 af[2], bfr[2];
            #pragma unroll
            for (int mi = 0; mi < 2; ++mi)
                af[mi] = *(const s16x8*)(As + (size_t)(wave * 32 + mi * 16 + (lane & 15)) * 64 + soff);
            #pragma unroll
            for (int ni = 0; ni < 2; ++ni)
                bfr[ni] = *(const s16x8*)(Bs + (size_t)(ni * 16 + (lane & 15)) * 64 + soff);
            #pragma unroll
            for (int mi = 0; mi < 2; ++mi)
                #pragma unroll
                for (int ni = 0; ni < 2; ++ni)
                    acc[mi][ni] = __builtin_amdgcn_mfma_f32_16x16x32_bf16(af[mi], bfr[ni], acc[mi][ni], 0, 0, 0);
        }
    }

    int col = lane & 15;
    float part = 0.f;
    #pragma unroll
    for (int ni = 0; ni < 2; ++ni) {
        int j = ni * 16 + col;
        float b2v = b2[j];
        float w3v = W3[j];
        #pragma unroll
        for (int mi = 0; mi < 2; ++mi)
            #pragma unroll
            for (int r = 0; r < 4; ++r)
                part += tanhf(acc[mi][ni][r] + b2v) * w3v;
    }
    #pragma unroll
    for (int off = 32; off >= 1; off >>= 1) part += __shfl_down(part, off);
    if (lane == 0) red[wave] = part;
    __syncthreads();
    if (tid == 0) util[d] = (red[0] + red[1] + red[2] + red[3]) * (1.0f / (float)NPD) + b3[0];
}

__global__ __launch_bounds__(256) void final_kernel(const float* __restrict__ util, const float* __restrict__ dm,
                                                    const int* __restrict__ ia, const int* __restrict__ ib,
                                                    float* __restrict__ out) {
    int i = threadIdx.x;
    if (i < NDOCS) {
        float diff = util[ib[i]] - util[ia[i]];
        float a = dm[i ^ 1];
        out[i] = 1.0f / (1.0f + expf(-diff * a));
    }
}

// ---------------------------------------------------------------------------
// launch
// ---------------------------------------------------------------------------
extern "C" void kernel_launch(void* const* d_in, const int* in_sizes, int n_in,
                              void* d_out, int out_size, void* d_ws, size_t ws_size,
                              hipStream_t stream) {
    const float* x      = (const float*)d_in[0];
    const int*   ei     = (const int*)d_in[1];
    const int*   e_src  = ei;
    const int*   e_dst  = ei + NE;
    const float* attn   = (const float*)d_in[4];
    const int*   idx_a  = (const int*)d_in[5];
    const int*   idx_b  = (const int*)d_in[6];
    const float* W_in   = (const float*)d_in[7];
    const float* b_in   = (const float*)d_in[8];
    const float* W_hid  = (const float*)d_in[9];
    const float* b_hid  = (const float*)d_in[10];
    const float* W_out  = (const float*)d_in[11];
    const float* b_out  = (const float*)d_in[12];
    const float* W_fc1  = (const float*)d_in[13];
    const float* b_fc1  = (const float*)d_in[14];
    const float* W_fc2  = (const float*)d_in[15];
    const float* b_fc2  = (const float*)d_in[16];
    const float* W_fc3  = (const float*)d_in[17];
    const float* b_fc3  = (const float*)d_in[18];
    float* out = (float*)d_out;

    // workspace carve-up (16B-aligned by construction)
    char* p = (char*)d_ws;
    unsigned short* hw_bf  = (unsigned short*)p; p += (size_t)NN * DD * 2;   // 32 MB (also hosts xagg)
    unsigned short* h_bf   = (unsigned short*)p; p += (size_t)NN * DD * 2;   // 32 MB
    unsigned short* xb     = (unsigned short*)p; p += (size_t)NN * FIN * 2;  // 8 MB
    unsigned short* Wt_in  = (unsigned short*)p; p += (size_t)DD * FIN * 2;
    unsigned short* Wt_hid = (unsigned short*)p; p += (size_t)DD * DD * 2;
    unsigned short* Wt_out = (unsigned short*)p; p += (size_t)DD * DD * 2;
    unsigned short* Wt_fc1 = (unsigned short*)p; p += (size_t)DD * DD * 2;
    unsigned short* W2t    = (unsigned short*)p; p += (size_t)32 * DD * 2;
    int*   cnt      = (int*)p;   p += (size_t)NN * 4;
    int*   cursor   = (int*)p;   p += (size_t)NN * 4;
    float* dis      = (float*)p; p += (size_t)NN * 4;
    float* dm       = (float*)p; p += (size_t)NDOCS * 4;
    float* util     = (float*)p; p += (size_t)NDOCS * 4;
    float* csr_norm = (float*)p; p += (size_t)NN * ECAP * 4;   // 4 MB
    int*   csr_src  = (int*)p;   p += (size_t)NN * ECAP * 4;   // 4 MB
    unsigned short* xagg = hw_bf;   // 8 MB, aliases hw_bf (free before layer-1 GEMM writes h_bf)

    // graph structure (no prefix scan: fixed-stride CSR)
    zero2<<<NN / 256, 256, 0, stream>>>(cnt, cursor);
    count_deg<<<NE / 256, 256, 0, stream>>>(e_dst, cnt);
    dis_k<<<NN / 256, 256, 0, stream>>>(cnt, dis);
    fill_csr<<<NE / 256, 256, 0, stream>>>(e_src, e_dst, dis, cursor, csr_src, csr_norm);
    doc_attn<<<NDOCS, 128, 0, stream>>>(attn, dm);

    // dtype prep (single fused launch)
    prep_cvt<<<7488, 256, 0, stream>>>(x, xb, W_in, Wt_in, W_hid, Wt_hid,
                                       W_out, Wt_out, W_fc1, Wt_fc1, W_fc2, W2t);

    int ngemm = (NN / 128) * (DD / 64);   // 2048 blocks, 1-D grid (XCD swizzle inside)
    int nagg  = NN / 8;                   // half-dispatch grids (4096 blocks)

    // layer 1: aggregate x first (A_norm x) @ W_in, fused bias+tanh
    agg_x<<<NN / 4, 256, 0, stream>>>(xb, dis, cnt, csr_src, csr_norm, xagg);
    mfma_gemm<true><<<ngemm, 256, 0, stream>>>(xagg, Wt_in, b_in, h_bf, NN, DD, FIN);
    // layer 2
    mfma_gemm<false><<<ngemm, 256, 0, stream>>>(h_bf, Wt_hid, nullptr, hw_bf, NN, DD, DD);
    agg_bf<<<nagg, 256, 0, stream>>>(hw_bf, dis, cnt, csr_src, csr_norm, b_hid, h_bf, 0);
    agg_bf<<<nagg, 256, 0, stream>>>(hw_bf, dis, cnt, csr_src, csr_norm, b_hid, h_bf, NN / 2);
    // layer 3
    mfma_gemm<false><<<ngemm, 256, 0, stream>>>(h_bf, Wt_hid, nullptr, hw_bf, NN, DD, DD);
    agg_bf<<<nagg, 256, 0, stream>>>(hw_bf, dis, cnt, csr_src, csr_norm, b_hid, h_bf, 0);
    agg_bf<<<nagg, 256, 0, stream>>>(hw_bf, dis, cnt, csr_src, csr_norm, b_hid, h_bf, NN / 2);
    // layer 4
    mfma_gemm<false><<<ngemm, 256, 0, stream>>>(h_bf, Wt_out, nullptr, hw_bf, NN, DD, DD);
    agg_bf<<<nagg, 256, 0, stream>>>(hw_bf, dis, cnt, csr_src, csr_norm, b_out, h_bf, 0);
    agg_bf<<<nagg, 256, 0, stream>>>(hw_bf, dis, cnt, csr_src, csr_norm, b_out, h_bf, NN / 2);
    // fc1 (fused bias+tanh)
    mfma_gemm<true><<<ngemm, 256, 0, stream>>>(h_bf, Wt_fc1, b_fc1, hw_bf, NN, DD, DD);
    // fc2+fc3+pool fused
    fc23_pool<<<NDOCS, 256, 0, stream>>>(hw_bf, W2t, b_fc2, W_fc3, b_fc3, util);
    // readout
    final_kernel<<<1, 256, 0, stream>>>(util, dm, idx_a, idx_b, out);
}

// Round 11
// 432.904 us; speedup vs baseline: 1.1276x; 1.1276x over previous
//
#include <hip/hip_runtime.h>
#include <hip/hip_bf16.h>
#include <hip/hip_fp8.h>
#include <math.h>

#define NN    32768      // nodes
#define FIN   128        // input features
#define DD    512        // hidden dim
#define NDOCS 256        // documents
#define NE    262144     // edges
#define NPD   128        // nodes per doc
#define ECAP  32         // fixed CSR capacity per node (P(deg>32) ~ 1e-12)

typedef __attribute__((ext_vector_type(8))) short s16x8;
typedef __attribute__((ext_vector_type(4))) float f32x4;

__device__ __forceinline__ unsigned short f2bf(float f) {
    union { float f; unsigned int u; } v; v.f = f;
    unsigned int r = (v.u + 0x7FFFu + ((v.u >> 16) & 1u)) >> 16;
    return (unsigned short)r;
}
__device__ __forceinline__ float bf2f(unsigned short h) {
    union { unsigned int u; float f; } v; v.u = ((unsigned int)h) << 16;
    return v.f;
}
// OCP fp8 e4m3 encode/decode via HIP types (hardware cvt on gfx950)
__device__ __forceinline__ unsigned char f2e4m3(float f) {
    __hip_fp8_e4m3 q(f);
    return (unsigned char)q.__x;
}
__device__ __forceinline__ float e4m3f(unsigned char b) {
    __hip_fp8_e4m3 q; q.__x = (__hip_fp8_storage_t)b;
    return (float)q;
}
__device__ __forceinline__ void dec8(uint2 u, float* f) {
    f[0] = e4m3f((unsigned char)(u.x       ));
    f[1] = e4m3f((unsigned char)(u.x >>  8 ));
    f[2] = e4m3f((unsigned char)(u.x >> 16 ));
    f[3] = e4m3f((unsigned char)(u.x >> 24 ));
    f[4] = e4m3f((unsigned char)(u.y       ));
    f[5] = e4m3f((unsigned char)(u.y >>  8 ));
    f[6] = e4m3f((unsigned char)(u.y >> 16 ));
    f[7] = e4m3f((unsigned char)(u.y >> 24 ));
}

__device__ __forceinline__ void gl2lds16(const void* g, void* l) {
    __builtin_amdgcn_global_load_lds(
        (const __attribute__((address_space(1))) int*)g,
        (__attribute__((address_space(3))) int*)l, 16, 0, 0);
}

// ---------------------------------------------------------------------------
// graph structure build (fixed-stride CSR: no prefix scan)
// ---------------------------------------------------------------------------
__global__ __launch_bounds__(256) void zero2(int* __restrict__ cnt, int* __restrict__ cursor) {
    int i = blockIdx.x * 256 + threadIdx.x;
    if (i < NN) { cnt[i] = 0; cursor[i] = 0; }
}

__global__ __launch_bounds__(256) void count_deg(const int* __restrict__ dst, int* __restrict__ cnt) {
    int e = blockIdx.x * 256 + threadIdx.x;
    if (e < NE) atomicAdd(&cnt[dst[e]], 1);
}

__global__ __launch_bounds__(256) void dis_k(const int* __restrict__ cnt, float* __restrict__ dis) {
    int i = blockIdx.x * 256 + threadIdx.x;
    if (i < NN) dis[i] = rsqrtf((float)(cnt[i] + 1));
}

__global__ __launch_bounds__(256) void fill_csr(const int* __restrict__ src, const int* __restrict__ dst,
                                                const float* __restrict__ dis,
                                                int* __restrict__ cursor, int* __restrict__ csr_src,
                                                float* __restrict__ csr_norm) {
    int e = blockIdx.x * 256 + threadIdx.x;
    if (e < NE) {
        int d = dst[e];
        int s = src[e];
        int pos = atomicAdd(&cursor[d], 1);
        if (pos < ECAP) {
            csr_src[d * ECAP + pos]  = s;
            csr_norm[d * ECAP + pos] = dis[s] * dis[d];
        }
    }
}

__global__ __launch_bounds__(128) void doc_attn(const float* __restrict__ attn, float* __restrict__ dm) {
    int d = blockIdx.x;
    int t = threadIdx.x;
    float v = attn[d * NPD + t];
    #pragma unroll
    for (int off = 32; off >= 1; off >>= 1) v += __shfl_down(v, off);
    __shared__ float sm[2];
    if ((t & 63) == 0) sm[t >> 6] = v;
    __syncthreads();
    if (t == 0) dm[d] = (sm[0] + sm[1]) * (1.0f / (float)NPD);
}

// ---------------------------------------------------------------------------
// fused dtype prep: x->bf16 and all weight transposes in ONE launch.
// ---------------------------------------------------------------------------
__global__ __launch_bounds__(256) void prep_cvt(const float* __restrict__ x,  unsigned short* __restrict__ xb,
                                                const float* __restrict__ Wi, unsigned short* __restrict__ Wti,
                                                const float* __restrict__ Wh, unsigned short* __restrict__ Wth,
                                                const float* __restrict__ Wo, unsigned short* __restrict__ Wto,
                                                const float* __restrict__ W1, unsigned short* __restrict__ Wt1,
                                                const float* __restrict__ W2, unsigned short* __restrict__ W2t) {
    int idx = blockIdx.x * 256 + threadIdx.x;
    if (idx < 1048576) {                       // cvt_x (float4 units)
        float4 v = ((const float4*)x)[idx];
        ushort4 o;
        o.x = f2bf(v.x); o.y = f2bf(v.y); o.z = f2bf(v.z); o.w = f2bf(v.w);
        ((ushort4*)xb)[idx] = o;
        return;
    }
    idx -= 1048576;
    if (idx < 65536)  { int k = idx >> 9, n = idx & 511; Wti[(size_t)n * FIN + k] = f2bf(Wi[idx]); return; }
    idx -= 65536;
    if (idx < 262144) { int k = idx >> 9, n = idx & 511; Wth[(size_t)n * DD + k] = f2bf(Wh[idx]); return; }
    idx -= 262144;
    if (idx < 262144) { int k = idx >> 9, n = idx & 511; Wto[(size_t)n * DD + k] = f2bf(Wo[idx]); return; }
    idx -= 262144;
    if (idx < 262144) { int k = idx >> 9, n = idx & 511; Wt1[(size_t)n * DD + k] = f2bf(W1[idx]); return; }
    idx -= 262144;
    if (idx < 16384)  { int k = idx >> 5, n = idx & 31;  W2t[(size_t)n * DD + k] = f2bf(W2[idx]); return; }
}

// ---------------------------------------------------------------------------
// MFMA bf16 GEMM: C[MxN] = A[MxK] @ Bt[NxK]^T
// 128x64 tile, 48 KB LDS (3 blocks/CU), T2 XOR swizzle, XCD-chunked block
// swizzle, T4 counted vmcnt(6). (r8 structure; GEMM < 41 us measured r10.)
// FP8OUT=false: fused bias+tanh, bf16 C (layer-1, fc1).
// FP8OUT=true : raw accum -> OCP e4m3 C (layers feeding the agg gather);
//               halves both GEMM write traffic and agg's gathered bytes.
// ---------------------------------------------------------------------------
template<bool FP8OUT>
__global__ __launch_bounds__(256) void mfma_gemm(const unsigned short* __restrict__ A,
                                                 const unsigned short* __restrict__ Bt,
                                                 const float* __restrict__ bias,
                                                 void* __restrict__ Cout,
                                                 int M, int N, int K) {
    __shared__ __align__(16) unsigned short As[2][128 * 64];   // 32 KB
    __shared__ __align__(16) unsigned short Bs[2][64 * 64];    // 16 KB
    int tid  = threadIdx.x;
    int lane = tid & 63;
    int wave = tid >> 6;

    // XCD-chunked bijective block swizzle (nwg % 8 == 0).
    int nwg  = gridDim.x;
    int bid  = blockIdx.x;
    int bsw  = (bid & 7) * (nwg >> 3) + (bid >> 3);
    int ntiles_n = N >> 6;
    int m0 = (bsw / ntiles_n) * 128;
    int n0 = (bsw % ntiles_n) * 64;

    int wm = wave * 32;            // wave's 32 m-rows; all 64 n-cols

    f32x4 zero = {0.f, 0.f, 0.f, 0.f};
    f32x4 acc[2][4];
    #pragma unroll
    for (int mi = 0; mi < 2; ++mi)
        #pragma unroll
        for (int ni = 0; ni < 4; ++ni) acc[mi][ni] = zero;

    int srow = tid >> 3;                               // 0..31
    // pre-swizzled global source column: slot ^ (row&7), 16B slots
    int scol = (((tid & 7) ^ ((tid >> 3) & 7)) * 8);
    const unsigned short* abase = A  + (size_t)(m0 + srow) * K + scol;
    const unsigned short* bbase = Bt + (size_t)(n0 + srow) * K + scol;

    // prologue: stage tile 0 into buffer 0 (6 vmem ops/wave)
    #pragma unroll
    for (int i = 0; i < 4; ++i)
        gl2lds16(abase + (size_t)i * 32 * K, &As[0][(size_t)(wave * 64 + i * 256) * 8]);
    gl2lds16(bbase,                  &Bs[0][(size_t)(wave * 64) * 8]);
    gl2lds16(bbase + (size_t)32 * K, &Bs[0][(size_t)(wave * 64 + 256) * 8]);

    int nk = K >> 6;
    for (int t = 0; t < nk; ++t) {
        int cur = t & 1;
        if (t + 1 < nk) {                      // stage next tile: 6 vmem ops
            int nxt = cur ^ 1;
            int k0n = (t + 1) << 6;
            #pragma unroll
            for (int i = 0; i < 4; ++i)
                gl2lds16(abase + (size_t)i * 32 * K + k0n, &As[nxt][(size_t)(wave * 64 + i * 256) * 8]);
            gl2lds16(bbase + k0n,                  &Bs[nxt][(size_t)(wave * 64) * 8]);
            gl2lds16(bbase + (size_t)32 * K + k0n, &Bs[nxt][(size_t)(wave * 64 + 256) * 8]);
            asm volatile("s_waitcnt vmcnt(6)" ::: "memory");   // prev tile staged
        } else {
            asm volatile("s_waitcnt vmcnt(0)" ::: "memory");   // last tile staged
        }
        __builtin_amdgcn_s_barrier();          // B1: buf[cur] visible to all

        s16x8 af[2][2], bfr[4][2];
        #pragma unroll
        for (int ks = 0; ks < 2; ++ks) {
            int soff = (((ks * 4 + (lane >> 4)) ^ (lane & 7)) << 3);   // row&7 == lane&7
            int ar = wm + (lane & 15);
            int br = lane & 15;
            #pragma unroll
            for (int mi = 0; mi < 2; ++mi)
                af[mi][ks] = *(const s16x8*)(&As[cur][0] + (size_t)(ar + mi * 16) * 64 + soff);
            #pragma unroll
            for (int ni = 0; ni < 4; ++ni)
                bfr[ni][ks] = *(const s16x8*)(&Bs[cur][0] + (size_t)(br + ni * 16) * 64 + soff);
        }
        asm volatile("s_waitcnt lgkmcnt(0)" ::: "memory");     // reads retired
        if (t + 1 < nk) __builtin_amdgcn_s_barrier();          // B2: safe to overwrite

        #pragma unroll
        for (int ks = 0; ks < 2; ++ks)
            #pragma unroll
            for (int mi = 0; mi < 2; ++mi)
                #pragma unroll
                for (int ni = 0; ni < 4; ++ni)
                    acc[mi][ni] = __builtin_amdgcn_mfma_f32_16x16x32_bf16(af[mi][ks], bfr[ni][ks], acc[mi][ni], 0, 0, 0);
    }

    int col = lane & 15;
    int rb  = (lane >> 4) * 4;
    #pragma unroll
    for (int ni = 0; ni < 4; ++ni) {
        int n = n0 + ni * 16 + col;
        float bv = 0.f;
        if (!FP8OUT) bv = bias[n];
        #pragma unroll
        for (int mi = 0; mi < 2; ++mi) {
            size_t base = (size_t)(m0 + wm + mi * 16 + rb) * N + n;
            #pragma unroll
            for (int r = 0; r < 4; ++r) {
                float v = acc[mi][ni][r];
                if (FP8OUT) {
                    ((unsigned char*)Cout)[base + (size_t)r * N] = f2e4m3(v);
                } else {
                    v = tanhf(v + bv);
                    ((unsigned short*)Cout)[base + (size_t)r * N] = f2bf(v);
                }
            }
        }
    }
}

// ---------------------------------------------------------------------------
// 512-wide aggregation, fp8-e4m3 in / bf16 out, one wave per node.
// The gathered array is 16 MB (fp8) instead of 32 MB (bf16): half the
// random-gather bytes and a footprint that fits better in L2 -> lower
// refetch. fp32 accumulate, bias+tanh epilogue unchanged.
// ---------------------------------------------------------------------------
__global__ __launch_bounds__(256) void agg_bf(const unsigned char* __restrict__ hw8,
                                              const float* __restrict__ dis,
                                              const int* __restrict__ cnt,
                                              const int* __restrict__ csr_src,
                                              const float* __restrict__ csr_norm,
                                              const float* __restrict__ bias,
                                              unsigned short* __restrict__ out) {
    int n = blockIdx.x * 4 + (threadIdx.x >> 6);
    int lane = threadIdx.x & 63;
    int cb = lane * 8;             // 8 fp8 columns = 8 B per lane
    int deg = cnt[n];
    int dcap = deg > ECAP ? ECAP : deg;

    int   sidx  = 0;
    float snorm = 0.f;
    if (lane < dcap) {
        sidx  = csr_src[n * ECAP + lane];
        snorm = csr_norm[n * ECAP + lane];
    }

    float dn = dis[n];
    float sw = dn * dn;
    float acc[8], fv[8];
    uint2 v = *(const uint2*)(hw8 + (size_t)n * DD + cb);
    dec8(v, fv);
    #pragma unroll
    for (int j = 0; j < 8; ++j) acc[j] = fv[j] * sw;

    for (int j0 = 0; j0 < dcap; j0 += 4) {
        int   s0 = __shfl(sidx, j0);
        int   s1 = __shfl(sidx, j0 + 1);
        int   s2 = __shfl(sidx, j0 + 2);
        int   s3 = __shfl(sidx, j0 + 3);
        float w0 = __shfl(snorm, j0);
        float w1 = __shfl(snorm, j0 + 1);
        float w2 = __shfl(snorm, j0 + 2);
        float w3 = __shfl(snorm, j0 + 3);
        uint2 u0 = *(const uint2*)(hw8 + (size_t)s0 * DD + cb);
        uint2 u1 = *(const uint2*)(hw8 + (size_t)s1 * DD + cb);
        uint2 u2 = *(const uint2*)(hw8 + (size_t)s2 * DD + cb);
        uint2 u3 = *(const uint2*)(hw8 + (size_t)s3 * DD + cb);
        float f0[8], f1[8], f2[8], f3[8];
        dec8(u0, f0); dec8(u1, f1); dec8(u2, f2); dec8(u3, f3);
        #pragma unroll
        for (int j = 0; j < 8; ++j) {
            acc[j] += w0 * f0[j];
            acc[j] += w1 * f1[j];
            acc[j] += w2 * f2[j];
            acc[j] += w3 * f3[j];
        }
    }

    s16x8 o;
    #pragma unroll
    for (int j = 0; j < 8; ++j)
        o[j] = (short)f2bf(tanhf(acc[j] + bias[cb + j]));
    *(s16x8*)(out + (size_t)n * DD + cb) = o;
}

// ---------------------------------------------------------------------------
// layer-1 pre-aggregation on 128-wide x (bf16 in/out, fp32 accum)
// ---------------------------------------------------------------------------
__global__ __launch_bounds__(256) void agg_x(const unsigned short* __restrict__ xb,
                                             const float* __restrict__ dis,
                                             const int* __restrict__ cnt,
                                             const int* __restrict__ csr_src,
                                             const float* __restrict__ csr_norm,
                                             unsigned short* __restrict__ xagg) {
    int n = blockIdx.x * 4 + (threadIdx.x >> 6);
    int lane = threadIdx.x & 63;
    int cb = lane * 2;
    int deg = cnt[n];
    int dcap = deg > ECAP ? ECAP : deg;

    int   sidx  = 0;
    float snorm = 0.f;
    if (lane < dcap) {
        sidx  = csr_src[n * ECAP + lane];
        snorm = csr_norm[n * ECAP + lane];
    }

    float dn = dis[n];
    float sw = dn * dn;
    unsigned int v = *(const unsigned int*)(xb + (size_t)n * FIN + cb);
    float a0 = bf2f((unsigned short)(v & 0xffffu)) * sw;
    float a1 = bf2f((unsigned short)(v >> 16)) * sw;

    for (int j0 = 0; j0 < dcap; j0 += 8) {
        int   s[8];
        float w[8];
        #pragma unroll
        for (int t = 0; t < 8; ++t) {
            s[t] = __shfl(sidx, j0 + t);
            w[t] = __shfl(snorm, j0 + t);
        }
        unsigned int u[8];
        #pragma unroll
        for (int t = 0; t < 8; ++t)
            u[t] = *(const unsigned int*)(xb + (size_t)s[t] * FIN + cb);
        #pragma unroll
        for (int t = 0; t < 8; ++t) {
            a0 += w[t] * bf2f((unsigned short)(u[t] & 0xffffu));
            a1 += w[t] * bf2f((unsigned short)(u[t] >> 16));
        }
    }
    unsigned int o = (unsigned int)f2bf(a0) | ((unsigned int)f2bf(a1) << 16);
    *(unsigned int*)(xagg + (size_t)n * FIN + cb) = o;
}

// ---------------------------------------------------------------------------
// fused fc2+fc3+pool: one block per doc (128 nodes), MFMA 128x32, K=512
// ---------------------------------------------------------------------------
__global__ __launch_bounds__(256) void fc23_pool(const unsigned short* __restrict__ H,
                                                 const unsigned short* __restrict__ W2t,
                                                 const float* __restrict__ b2,
                                                 const float* __restrict__ W3,
                                                 const float* __restrict__ b3,
                                                 float* __restrict__ util) {
    __shared__ __align__(16) unsigned short As[128 * 64];
    __shared__ __align__(16) unsigned short Bs[32 * 64];
    __shared__ float red[4];
    int d = blockIdx.x;
    int tid = threadIdx.x;
    int lane = tid & 63;
    int wave = tid >> 6;
    const unsigned short* A = H + (size_t)d * NPD * DD;

    f32x4 zero = {0.f, 0.f, 0.f, 0.f};
    f32x4 acc[2][2];
    #pragma unroll
    for (int mi = 0; mi < 2; ++mi)
        #pragma unroll
        for (int ni = 0; ni < 2; ++ni) acc[mi][ni] = zero;

    int srow = tid >> 3;
    int scol = (((tid & 7) ^ ((tid >> 3) & 7)) * 8);
    for (int k0 = 0; k0 < DD; k0 += 64) {
        __syncthreads();
        #pragma unroll
        for (int i = 0; i < 4; ++i)
            gl2lds16(A + (size_t)(srow + i * 32) * DD + k0 + scol,
                     As + (size_t)(wave * 64 + i * 256) * 8);
        gl2lds16(W2t + (size_t)srow * DD + k0 + scol, Bs + (size_t)(wave * 64) * 8);
        __syncthreads();
        #pragma unroll
        for (int ks = 0; ks < 2; ++ks) {
            int slotbase = ks * 4 + (lane >> 4);
            int soff = ((slotbase ^ (lane & 7)) << 3);
            s16x8 af[2], bfr[2];
            #pragma unroll
            for (int mi = 0; mi < 2; ++mi)
                af[mi] = *(const s16x8*)(As + (size_t)(wave * 32 + mi * 16 + (lane & 15)) * 64 + soff);
            #pragma unroll
            for (int ni = 0; ni < 2; ++ni)
                bfr[ni] = *(const s16x8*)(Bs + (size_t)(ni * 16 + (lane & 15)) * 64 + soff);
            #pragma unroll
            for (int mi = 0; mi < 2; ++mi)
                #pragma unroll
                for (int ni = 0; ni < 2; ++ni)
                    acc[mi][ni] = __builtin_amdgcn_mfma_f32_16x16x32_bf16(af[mi], bfr[ni], acc[mi][ni], 0, 0, 0);
        }
    }

    int col = lane & 15;
    float part = 0.f;
    #pragma unroll
    for (int ni = 0; ni < 2; ++ni) {
        int j = ni * 16 + col;
        float b2v = b2[j];
        float w3v = W3[j];
        #pragma unroll
        for (int mi = 0; mi < 2; ++mi)
            #pragma unroll
            for (int r = 0; r < 4; ++r)
                part += tanhf(acc[mi][ni][r] + b2v) * w3v;
    }
    #pragma unroll
    for (int off = 32; off >= 1; off >>= 1) part += __shfl_down(part, off);
    if (lane == 0) red[wave] = part;
    __syncthreads();
    if (tid == 0) util[d] = (red[0] + red[1] + red[2] + red[3]) * (1.0f / (float)NPD) + b3[0];
}

__global__ __launch_bounds__(256) void final_kernel(const float* __restrict__ util, const float* __restrict__ dm,
                                                    const int* __restrict__ ia, const int* __restrict__ ib,
                                                    float* __restrict__ out) {
    int i = threadIdx.x;
    if (i < NDOCS) {
        float diff = util[ib[i]] - util[ia[i]];
        float a = dm[i ^ 1];
        out[i] = 1.0f / (1.0f + expf(-diff * a));
    }
}

// ---------------------------------------------------------------------------
// launch
// ---------------------------------------------------------------------------
extern "C" void kernel_launch(void* const* d_in, const int* in_sizes, int n_in,
                              void* d_out, int out_size, void* d_ws, size_t ws_size,
                              hipStream_t stream) {
    const float* x      = (const float*)d_in[0];
    const int*   ei     = (const int*)d_in[1];
    const int*   e_src  = ei;
    const int*   e_dst  = ei + NE;
    const float* attn   = (const float*)d_in[4];
    const int*   idx_a  = (const int*)d_in[5];
    const int*   idx_b  = (const int*)d_in[6];
    const float* W_in   = (const float*)d_in[7];
    const float* b_in   = (const float*)d_in[8];
    const float* W_hid  = (const float*)d_in[9];
    const float* b_hid  = (const float*)d_in[10];
    const float* W_out  = (const float*)d_in[11];
    const float* b_out  = (const float*)d_in[12];
    const float* W_fc1  = (const float*)d_in[13];
    const float* b_fc1  = (const float*)d_in[14];
    const float* W_fc2  = (const float*)d_in[15];
    const float* b_fc2  = (const float*)d_in[16];
    const float* W_fc3  = (const float*)d_in[17];
    const float* b_fc3  = (const float*)d_in[18];
    float* out = (float*)d_out;

    // workspace carve-up (16B-aligned by construction)
    char* p = (char*)d_ws;
    unsigned short* hw_bf  = (unsigned short*)p; p += (size_t)NN * DD * 2;   // 32 MB (xagg + fc1 out)
    unsigned short* h_bf   = (unsigned short*)p; p += (size_t)NN * DD * 2;   // 32 MB
    unsigned short* xb     = (unsigned short*)p; p += (size_t)NN * FIN * 2;  // 8 MB
    unsigned short* Wt_in  = (unsigned short*)p; p += (size_t)DD * FIN * 2;
    unsigned short* Wt_hid = (unsigned short*)p; p += (size_t)DD * DD * 2;
    unsigned short* Wt_out = (unsigned short*)p; p += (size_t)DD * DD * 2;
    unsigned short* Wt_fc1 = (unsigned short*)p; p += (size_t)DD * DD * 2;
    unsigned short* W2t    = (unsigned short*)p; p += (size_t)32 * DD * 2;
    int*   cnt      = (int*)p;   p += (size_t)NN * 4;
    int*   cursor   = (int*)p;   p += (size_t)NN * 4;
    float* dis      = (float*)p; p += (size_t)NN * 4;
    float* dm       = (float*)p; p += (size_t)NDOCS * 4;
    float* util     = (float*)p; p += (size_t)NDOCS * 4;
    float* csr_norm = (float*)p; p += (size_t)NN * ECAP * 4;   // 4 MB
    int*   csr_src  = (int*)p;   p += (size_t)NN * ECAP * 4;   // 4 MB
    unsigned char* hw8 = (unsigned char*)p; p += (size_t)NN * DD;   // 16 MB fp8 gather array
    unsigned short* xagg = hw_bf;   // 8 MB, aliases hw_bf (free before layer-1 GEMM writes h_bf)

    // graph structure (no prefix scan: fixed-stride CSR)
    zero2<<<NN / 256, 256, 0, stream>>>(cnt, cursor);
    count_deg<<<NE / 256, 256, 0, stream>>>(e_dst, cnt);
    dis_k<<<NN / 256, 256, 0, stream>>>(cnt, dis);
    fill_csr<<<NE / 256, 256, 0, stream>>>(e_src, e_dst, dis, cursor, csr_src, csr_norm);
    doc_attn<<<NDOCS, 128, 0, stream>>>(attn, dm);

    // dtype prep (single fused launch)
    prep_cvt<<<7488, 256, 0, stream>>>(x, xb, W_in, Wt_in, W_hid, Wt_hid,
                                       W_out, Wt_out, W_fc1, Wt_fc1, W_fc2, W2t);

    int ngemm = (NN / 128) * (DD / 64);   // 2048 blocks, 1-D grid (XCD swizzle inside)

    // layer 1: aggregate x first (A_norm x) @ W_in, fused bias+tanh -> bf16 h
    agg_x<<<NN / 4, 256, 0, stream>>>(xb, dis, cnt, csr_src, csr_norm, xagg);
    mfma_gemm<false><<<ngemm, 256, 0, stream>>>(xagg, Wt_in, b_in, h_bf, NN, DD, FIN);
    // layer 2: GEMM -> fp8, agg gathers fp8, writes bf16 h
    mfma_gemm<true><<<ngemm, 256, 0, stream>>>(h_bf, Wt_hid, nullptr, hw8, NN, DD, DD);
    agg_bf<<<NN / 4, 256, 0, stream>>>(hw8, dis, cnt, csr_src, csr_norm, b_hid, h_bf);
    // layer 3
    mfma_gemm<true><<<ngemm, 256, 0, stream>>>(h_bf, Wt_hid, nullptr, hw8, NN, DD, DD);
    agg_bf<<<NN / 4, 256, 0, stream>>>(hw8, dis, cnt, csr_src, csr_norm, b_hid, h_bf);
    // layer 4
    mfma_gemm<true><<<ngemm, 256, 0, stream>>>(h_bf, Wt_out, nullptr, hw8, NN, DD, DD);
    agg_bf<<<NN / 4, 256, 0, stream>>>(hw8, dis, cnt, csr_src, csr_norm, b_out, h_bf);
    // fc1 (fused bias+tanh, bf16 out)
    mfma_gemm<false><<<ngemm, 256, 0, stream>>>(h_bf, Wt_fc1, b_fc1, hw_bf, NN, DD, DD);
    // fc2+fc3+pool fused
    fc23_pool<<<NDOCS, 256, 0, stream>>>(hw_bf, W2t, b_fc2, W_fc3, b_fc3, util);
    // readout
    final_kernel<<<1, 256, 0, stream>>>(util, dm, idx_a, idx_b, out);
}